// Round 11
// baseline (263.489 us; speedup 1.0000x reference)
//
#include <hip/hip_runtime.h>

typedef __bf16 bf16;
typedef __attribute__((ext_vector_type(4))) __bf16 bf16x4;
typedef __attribute__((ext_vector_type(8))) __bf16 bf16x8;
typedef __attribute__((ext_vector_type(4))) float f32x4;
typedef __attribute__((ext_vector_type(4))) unsigned int u32x4;

#define B_ 4
#define S_ 2048
#define D_ 1024
#define H_ 16
#define HD_ 64

#define GLB(p) ((const __attribute__((address_space(1))) void*)(p))
#define LDS(p) ((__attribute__((address_space(3))) void*)(p))

// ---------------- pass 0: fused prep ----------------
// z<4: weight transpose+convert (K,N)fp32 -> (N,K)bf16 (one W per z).
// z>=4: X fp32 -> bf16 (4096 linear blocks).
__global__ __launch_bounds__(256) void prep(
    const float* __restrict__ W0, const float* __restrict__ W1,
    const float* __restrict__ W2, const float* __restrict__ W3,
    bf16* __restrict__ T0, bf16* __restrict__ T1,
    bf16* __restrict__ T2, bf16* __restrict__ T3,
    const float* __restrict__ X, bf16* __restrict__ Xb)
{
    __shared__ float tile[32][33];
    const int z = blockIdx.z;
    if (z < 4) {
        const float* W = (z == 0) ? W0 : (z == 1) ? W1 : (z == 2) ? W2 : W3;
        bf16*        T = (z == 0) ? T0 : (z == 1) ? T1 : (z == 2) ? T2 : T3;
        int bx = blockIdx.x * 32, by = blockIdx.y * 32;
        int tx = threadIdx.x & 31, ty = threadIdx.x >> 5;
        #pragma unroll
        for (int j = 0; j < 32; j += 8)
            tile[ty + j][tx] = W[(size_t)(by + ty + j) * D_ + bx + tx];
        __syncthreads();
        #pragma unroll
        for (int j = 0; j < 32; j += 8)
            T[(size_t)(bx + ty + j) * D_ + by + tx] = (bf16)tile[tx][ty + j];
    } else {
        int lin = (z - 4) * 1024 + blockIdx.y * 32 + blockIdx.x;
        size_t i = ((size_t)lin * 256 + threadIdx.x) * 8;
        f32x4 a = *(const f32x4*)(X + i);
        f32x4 b = *(const f32x4*)(X + i + 4);
        bf16x8 v;
        #pragma unroll
        for (int j = 0; j < 4; ++j) { v[j] = (bf16)a[j]; v[4 + j] = (bf16)b[j]; }
        *(bf16x8*)(Xb + i) = v;
    }
}

// ---------------- pass 1: fused QKV projection GEMM ----------------
// v8 VERBATIM (verified best: 74.5us, SQ_LDS_BANK_CONFLICT=0).
__global__ __launch_bounds__(256) void qkv_gemm(
    const bf16* __restrict__ Xb,
    const bf16* __restrict__ WqT, const bf16* __restrict__ WkT, const bf16* __restrict__ WvT,
    const float* __restrict__ bq, const float* __restrict__ bk, const float* __restrict__ bv,
    bf16* __restrict__ Qo, bf16* __restrict__ Ko, bf16* __restrict__ Vo)
{
    const int lin = blockIdx.x + (blockIdx.y << 3) + (blockIdx.z << 9);
    const int xcd = lin & 7, rest = lin >> 3;
    const int byb = xcd * 8 + (rest & 7);
    const int bxb = (rest >> 3) & 7;
    const int z   = rest >> 6;

    const bf16*  WT   = (z == 0) ? WqT : (z == 1) ? WkT : WvT;
    const float* bias = (z == 0) ? bq  : (z == 1) ? bk  : bv;
    bf16*        out  = (z == 0) ? Qo  : (z == 1) ? Ko  : Vo;
    const float scale = (z == 0) ? 0.18033688011112042f : 1.0f;

    __shared__ bf16 As[128 * 64];
    __shared__ bf16 Bs[128 * 64];

    const int t = threadIdx.x;
    const int lid = t & 63, w = t >> 6;
    const int wm = w & 1, wn = w >> 1;
    const int lrow = lid & 15, quad = lid >> 4;
    const int m0 = byb * 128, n0 = bxb * 128;

    const bf16* Ag = Xb + (size_t)m0 * D_;
    const bf16* Bg = WT + (size_t)n0 * D_;

    const int srow = t >> 3;
    const int ssel = ((t & 7) ^ (srow & 7)) << 3;

    const int rsw = lrow & 7;

    f32x4 acc[4][4] = {};

    for (int k0 = 0; k0 < D_; k0 += 64) {
        __syncthreads();
        #pragma unroll
        for (int j = 0; j < 4; ++j) {
            __builtin_amdgcn_global_load_lds(
                GLB(Ag + (size_t)(srow + j * 32) * D_ + k0 + ssel),
                LDS((char*)As + j * 4096 + t * 16), 16, 0, 0);
            __builtin_amdgcn_global_load_lds(
                GLB(Bg + (size_t)(srow + j * 32) * D_ + k0 + ssel),
                LDS((char*)Bs + j * 4096 + t * 16), 16, 0, 0);
        }
        __syncthreads();
        #pragma unroll
        for (int kk = 0; kk < 2; ++kk) {
            const int ro = ((kk * 4 + quad) ^ rsw) << 4;
            bf16x8 a[4], b[4];
            #pragma unroll
            for (int mb = 0; mb < 4; ++mb)
                a[mb] = *(const bf16x8*)((const char*)As + (wm * 64 + mb * 16 + lrow) * 128 + ro);
            #pragma unroll
            for (int nb = 0; nb < 4; ++nb)
                b[nb] = *(const bf16x8*)((const char*)Bs + (wn * 64 + nb * 16 + lrow) * 128 + ro);
            #pragma unroll
            for (int mb = 0; mb < 4; ++mb)
                #pragma unroll
                for (int nb = 0; nb < 4; ++nb)
                    acc[mb][nb] = __builtin_amdgcn_mfma_f32_16x16x32_bf16(a[mb], b[nb], acc[mb][nb], 0, 0, 0);
        }
    }

    #pragma unroll
    for (int mb = 0; mb < 4; ++mb) {
        #pragma unroll
        for (int nb = 0; nb < 4; ++nb) {
            int gn = n0 + wn * 64 + nb * 16 + lrow;
            float bsv = bias[gn];
            int h = gn >> 6, hd = gn & 63;
            int gm0 = m0 + wm * 64 + mb * 16 + quad * 4;
            int bb = gm0 >> 11, s0 = gm0 & 2047;
            if (z == 2) {
                bf16x4 pk;
                #pragma unroll
                for (int r = 0; r < 4; ++r)
                    pk[r] = (bf16)(acc[mb][nb][r] + bsv);
                *(bf16x4*)(out + (((size_t)(bb * H_ + h)) * HD_ + hd) * S_ + s0) = pk;
            } else {
                #pragma unroll
                for (int r = 0; r < 4; ++r) {
                    float v = (acc[mb][nb][r] + bsv) * scale;
                    out[(((size_t)(bb * H_ + h)) * S_ + (s0 + r)) * HD_ + hd] = (bf16)v;
                }
            }
        }
    }
}

// ---------------- pass 2: causal flash attention (S-transposed scheme) -----
// v12 = v9 compute VERBATIM + barrier amortization: double-buffered K/V,
// stage TWO 64-key tiles per barrier-pair (at even kt), compute odd kt from
// buf1 with NO barriers (per-wave lgkmcnt covers the private P region).
// Barrier-pairs per wave: 33 -> 17; 8 staging loads issue together (MLP).
// LDS = 2*8K (K) + 2*8K (V) + 8K (P) = 40960 B -> 4 blocks/CU (grid-capped
// at 4 anyway; v3 falsified LDS-capacity as an occupancy driver at 40KB).
__global__ __launch_bounds__(256) void attn_fwd(
    const bf16* __restrict__ Q, const bf16* __restrict__ K,
    const bf16* __restrict__ Vt, bf16* __restrict__ O)
{
    __shared__ bf16 Ks[2][64 * 64];     // [buf][key][hd], XOR-swizzled
    __shared__ bf16 Vs[2][64 * 64];     // [buf][hd][key], XOR-swizzled
    __shared__ bf16 Ps[4][16 * 64];     // per-wave P [query][key], swizzled

    // T1 XCD-aware remap (bijective on 1024 blocks)
    const int lin = blockIdx.x + (blockIdx.y << 4);
    const int xcd = lin & 7;
    const int sl  = lin >> 3;
    const int bh  = xcd * 8 + (sl >> 4);
    const int bxp = sl & 15;

    const int t = threadIdx.x, lid = t & 63, w = t >> 6;
    const int lrow = lid & 15, quad = lid >> 4;
    const int b = bh >> 4, h = bh & 15;

    const int swz = (lrow & 7) << 4;

    const int srow0 = t >> 3, srow1 = srow0 + 32;     // srow1&7 == srow0&7
    const int k8 = (t & 7) << 3;
    const int sswz = ((t & 7) << 4) ^ ((srow0 & 7) << 4);
    const int off0 = srow0 * 128 + sswz;
    const int off1 = srow1 * 128 + sswz;

    bf16x8 onesv;
    #pragma unroll
    for (int j = 0; j < 8; ++j) onesv[j] = (bf16)1.0f;

    #pragma unroll 1
    for (int half = 0; half < 2; ++half) {
        const int qtile = half ? bxp : (31 - bxp);
        const int qbase = qtile * 64;

        const bf16* Qp = Q + ((size_t)bh * S_ + qbase + w * 16) * HD_;
        bf16x8 qf[2];
        #pragma unroll
        for (int ks = 0; ks < 2; ++ks)
            qf[ks] = *(const bf16x8*)(Qp + lrow * HD_ + ks * 32 + quad * 8);

        f32x4 o_acc[4] = {};
        f32x4 l_acc = {0.0f, 0.0f, 0.0f, 0.0f};
        float m_i = -3.0e4f;

        for (int kt = 0; kt <= qtile; ++kt) {
            const int buf = kt & 1;
            if (buf == 0) {
                // stage tiles kt (buf0) and kt+1 (buf1) under ONE barrier-pair
                const bf16* Kp = K  + ((size_t)bh * S_ + kt * 64) * HD_;
                const bf16* Vp = Vt + ((size_t)bh * HD_) * S_ + kt * 64;
                __syncthreads();
                u32x4 ka0 = *(const u32x4*)(Kp + (size_t)srow0 * HD_ + k8);
                u32x4 ka1 = *(const u32x4*)(Kp + (size_t)srow1 * HD_ + k8);
                u32x4 va0 = *(const u32x4*)(Vp + (size_t)srow0 * S_ + k8);
                u32x4 va1 = *(const u32x4*)(Vp + (size_t)srow1 * S_ + k8);
                *(u32x4*)((char*)Ks[0] + off0) = ka0;
                *(u32x4*)((char*)Ks[0] + off1) = ka1;
                *(u32x4*)((char*)Vs[0] + off0) = va0;
                *(u32x4*)((char*)Vs[0] + off1) = va1;
                if (kt < qtile) {
                    const bf16* Kn = Kp + 64 * HD_;
                    const bf16* Vn = Vp + 64;
                    u32x4 kb0 = *(const u32x4*)(Kn + (size_t)srow0 * HD_ + k8);
                    u32x4 kb1 = *(const u32x4*)(Kn + (size_t)srow1 * HD_ + k8);
                    u32x4 vb0 = *(const u32x4*)(Vn + (size_t)srow0 * S_ + k8);
                    u32x4 vb1 = *(const u32x4*)(Vn + (size_t)srow1 * S_ + k8);
                    *(u32x4*)((char*)Ks[1] + off0) = kb0;
                    *(u32x4*)((char*)Ks[1] + off1) = kb1;
                    *(u32x4*)((char*)Vs[1] + off0) = vb0;
                    *(u32x4*)((char*)Vs[1] + off1) = vb1;
                }
                __syncthreads();
            }

            const char* kb = (const char*)Ks[buf];
            const char* vb = (const char*)Vs[buf];

            f32x4 sa[4] = {};
            #pragma unroll
            for (int ks = 0; ks < 2; ++ks) {
                const int ro = ((ks << 6) + (quad << 4)) ^ swz;
                #pragma unroll
                for (int nb = 0; nb < 4; ++nb) {
                    bf16x8 kf = *(const bf16x8*)(kb + (nb * 16 + lrow) * 128 + ro);
                    sa[nb] = __builtin_amdgcn_mfma_f32_16x16x32_bf16(kf, qf[ks], sa[nb], 0, 0, 0);
                }
            }

            if (kt == qtile) {
                int q = qbase + w * 16 + lrow;
                #pragma unroll
                for (int nb = 0; nb < 4; ++nb) {
                    int key = kt * 64 + nb * 16 + quad * 4;
                    #pragma unroll
                    for (int r = 0; r < 4; ++r)
                        if (key + r > q) sa[nb][r] = -3.0e4f;
                }
            }

            // speculative softmax: p with OLD m_i issues immediately;
            // fmax tree in parallel; shuffles/rescale only on heavy path.
            float p[4][4];
            {
                #pragma unroll
                for (int nb = 0; nb < 4; ++nb)
                    #pragma unroll
                    for (int r = 0; r < 4; ++r)
                        p[nb][r] = __builtin_amdgcn_exp2f(sa[nb][r] - m_i);

                float r0 = fmaxf(fmaxf(sa[0][0], sa[0][1]), sa[0][2]);
                float r1 = fmaxf(fmaxf(sa[0][3], sa[1][0]), sa[1][1]);
                float r2 = fmaxf(fmaxf(sa[1][2], sa[1][3]), sa[2][0]);
                float r3 = fmaxf(fmaxf(sa[2][1], sa[2][2]), sa[2][3]);
                float r4 = fmaxf(fmaxf(sa[3][0], sa[3][1]), sa[3][2]);
                float rm = fmaxf(fmaxf(fmaxf(r0, r1), r2),
                                 fmaxf(fmaxf(r3, r4), sa[3][3]));

                if (!__all(rm <= m_i + 8.0f)) {
                    rm = fmaxf(rm, __shfl_xor(rm, 16));
                    rm = fmaxf(rm, __shfl_xor(rm, 32));
                    float mnew = fmaxf(m_i, rm);
                    float al = __builtin_amdgcn_exp2f(m_i - mnew);
                    m_i = mnew;
                    #pragma unroll
                    for (int nb = 0; nb < 4; ++nb)
                        #pragma unroll
                        for (int r = 0; r < 4; ++r) {
                            o_acc[nb][r] *= al;
                            p[nb][r] = __builtin_amdgcn_exp2f(sa[nb][r] - m_i);
                        }
                    #pragma unroll
                    for (int r = 0; r < 4; ++r)
                        l_acc[r] *= al;
                }
            }

            char* pw = (char*)Ps[w] + lrow * 128;
            #pragma unroll
            for (int nb = 0; nb < 4; ++nb) {
                bf16x4 pk;
                #pragma unroll
                for (int r = 0; r < 4; ++r)
                    pk[r] = (bf16)p[nb][r];
                *(bf16x4*)(pw + ((nb * 32 + quad * 8) ^ swz)) = pk;
            }
            asm volatile("s_waitcnt lgkmcnt(0)" ::: "memory");

            #pragma unroll
            for (int ks = 0; ks < 2; ++ks) {
                const int ro = ((ks << 6) + (quad << 4)) ^ swz;
                bf16x8 pf = *(const bf16x8*)(pw + ro);
                #pragma unroll
                for (int nb = 0; nb < 4; ++nb) {
                    bf16x8 vf = *(const bf16x8*)(vb + (nb * 16 + lrow) * 128 + ro);
                    o_acc[nb] = __builtin_amdgcn_mfma_f32_16x16x32_bf16(vf, pf, o_acc[nb], 0, 0, 0);
                }
                l_acc = __builtin_amdgcn_mfma_f32_16x16x32_bf16(onesv, pf, l_acc, 0, 0, 0);
            }
        }

        {
            float inv = 1.0f / l_acc[0];
            int s = qbase + w * 16 + lrow;
            #pragma unroll
            for (int nb = 0; nb < 4; ++nb) {
                bf16x4 pk;
                #pragma unroll
                for (int r = 0; r < 4; ++r)
                    pk[r] = (bf16)(o_acc[nb][r] * inv);
                *(bf16x4*)(O + ((size_t)b * S_ + s) * D_ + h * 64 + nb * 16 + quad * 4) = pk;
            }
        }
        __syncthreads();   // protect LDS before next half re-stages
    }
}

// ---------------- pass 3: output projection GEMM (fp32 out) ----------------
// v8 VERBATIM: BK=64 + swizzle + XCD remap (512 blocks).
__global__ __launch_bounds__(256) void proj_gemm(
    const bf16* __restrict__ A, const bf16* __restrict__ WpT,
    const float* __restrict__ bp, float* __restrict__ out)
{
    const int lin = blockIdx.x + (blockIdx.y << 3);
    const int xcd = lin & 7, rest = lin >> 3;
    const int byb = xcd * 8 + (rest & 7);
    const int bxb = rest >> 3;

    __shared__ bf16 As[128 * 64];
    __shared__ bf16 Bs[128 * 64];

    const int t = threadIdx.x;
    const int lid = t & 63, w = t >> 6;
    const int wm = w & 1, wn = w >> 1;
    const int lrow = lid & 15, quad = lid >> 4;
    const int m0 = byb * 128, n0 = bxb * 128;

    const bf16* Ag = A   + (size_t)m0 * D_;
    const bf16* Bg = WpT + (size_t)n0 * D_;

    const int srow = t >> 3;
    const int ssel = ((t & 7) ^ (srow & 7)) << 3;
    const int rsw = lrow & 7;

    f32x4 acc[4][4] = {};

    for (int k0 = 0; k0 < D_; k0 += 64) {
        __syncthreads();
        #pragma unroll
        for (int j = 0; j < 4; ++j) {
            __builtin_amdgcn_global_load_lds(
                GLB(Ag + (size_t)(srow + j * 32) * D_ + k0 + ssel),
                LDS((char*)As + j * 4096 + t * 16), 16, 0, 0);
            __builtin_amdgcn_global_load_lds(
                GLB(Bg + (size_t)(srow + j * 32) * D_ + k0 + ssel),
                LDS((char*)Bs + j * 4096 + t * 16), 16, 0, 0);
        }
        __syncthreads();
        #pragma unroll
        for (int kk = 0; kk < 2; ++kk) {
            const int ro = ((kk * 4 + quad) ^ rsw) << 4;
            bf16x8 a[4], b[4];
            #pragma unroll
            for (int mb = 0; mb < 4; ++mb)
                a[mb] = *(const bf16x8*)((const char*)As + (wm * 64 + mb * 16 + lrow) * 128 + ro);
            #pragma unroll
            for (int nb = 0; nb < 4; ++nb)
                b[nb] = *(const bf16x8*)((const char*)Bs + (wn * 64 + nb * 16 + lrow) * 128 + ro);
            #pragma unroll
            for (int mb = 0; mb < 4; ++mb)
                #pragma unroll
                for (int nb = 0; nb < 4; ++nb)
                    acc[mb][nb] = __builtin_amdgcn_mfma_f32_16x16x32_bf16(a[mb], b[nb], acc[mb][nb], 0, 0, 0);
        }
    }

    #pragma unroll
    for (int mb = 0; mb < 4; ++mb) {
        #pragma unroll
        for (int nb = 0; nb < 4; ++nb) {
            int gn = n0 + wn * 64 + nb * 16 + lrow;
            float bsv = bp[gn];
            #pragma unroll
            for (int r = 0; r < 4; ++r) {
                int gm = m0 + wm * 64 + mb * 16 + quad * 4 + r;
                out[(size_t)gm * D_ + gn] = acc[mb][nb][r] + bsv;
            }
        }
    }
}

// ---------------- launch ----------------
extern "C" void kernel_launch(void* const* d_in, const int* in_sizes, int n_in,
                              void* d_out, int out_size, void* d_ws, size_t ws_size,
                              hipStream_t stream)
{
    const float* x  = (const float*)d_in[0];
    const float* Wq = (const float*)d_in[1];
    const float* bq = (const float*)d_in[2];
    const float* Wk = (const float*)d_in[3];
    const float* bk = (const float*)d_in[4];
    const float* Wv = (const float*)d_in[5];
    const float* bv = (const float*)d_in[6];
    const float* Wp = (const float*)d_in[7];
    const float* bp = (const float*)d_in[8];

    bf16* ws = (bf16*)d_ws;
    const size_t WSZ = (size_t)D_ * D_;        // 1,048,576 elems
    const size_t BIG = (size_t)B_ * S_ * D_;   // 8,388,608 elems
    bf16* WqT = ws;
    bf16* WkT = WqT + WSZ;
    bf16* WvT = WkT + WSZ;
    bf16* WpT = WvT + WSZ;
    bf16* Qb  = WpT + WSZ;
    bf16* Kb  = Qb + BIG;
    bf16* Vb  = Kb + BIG;    // V^T layout [b,h,hd,s]
    bf16* Ab  = Vb + BIG;    // X(bf16) during qkv, then attention output

    prep<<<dim3(32, 32, 8), 256, 0, stream>>>(
        Wq, Wk, Wv, Wp, WqT, WkT, WvT, WpT, x, Ab);

    qkv_gemm<<<dim3(8, 64, 3), 256, 0, stream>>>(
        Ab, WqT, WkT, WvT, bq, bk, bv, Qb, Kb, Vb);

    attn_fwd<<<dim3(16, 64), 256, 0, stream>>>(Qb, Kb, Vb, Ab);

    proj_gemm<<<dim3(8, 64), 256, 0, stream>>>(Ab, WpT, bp, (float*)d_out);
}